// Round 1
// baseline (8024.994 us; speedup 1.0000x reference)
//
#include <hip/hip_runtime.h>
#include <math.h>

// LiftProjectNetwork:
//   8 lift layers:  g = l2norm(scatter_add(h[src]*w @ dst)); h = l2norm([h,g] @ W + b)
//   4 proj layers:  g = scatter_add(h[src]*w @ dst);         h = tanh([h,g] @ W + b)
// N=50000, E=1600000, r=32.

#define R 32
#define EPSN 1e-12f

// ---------------- scatter-add: g[dst] += h[src] * w ----------------
// 8 threads per edge, float4 (4 feats) per thread.
__global__ void scatter_kernel(const float* __restrict__ h,
                               const int* __restrict__ ei,   // [2*E] (src row, dst row)
                               const float* __restrict__ ew, // [E]
                               float* __restrict__ g,
                               int E) {
    long long t = (long long)blockIdx.x * blockDim.x + threadIdx.x;
    long long e = t >> 3;
    if (e >= E) return;
    int j0 = ((int)t & 7) * 4;
    int src = ei[e];
    int dst = ei[(long long)E + e];
    float w = ew[e];
    const float4 v = *reinterpret_cast<const float4*>(h + (long long)src * R + j0);
    float* gp = g + (long long)dst * R + j0;
    atomicAdd(gp + 0, v.x * w);
    atomicAdd(gp + 1, v.y * w);
    atomicAdd(gp + 2, v.z * w);
    atomicAdd(gp + 3, v.w * w);
}

// ---------------- per-node update ----------------
// block = 256 threads = 8 nodes x 32 lanes. Each lane owns one output feature.
// LDS: weight tile 64x32 (8KB) + per-node [h,g] rows.
template <bool LIFT>
__global__ void node_kernel(const float* __restrict__ h,
                            const float* __restrict__ g,
                            const float* __restrict__ W,  // [64*32] row-major (k, j)
                            const float* __restrict__ b,  // [32]
                            float* __restrict__ out,
                            int N) {
    __shared__ float Ws[64 * R];
    __shared__ float hg[8][64];

    for (int i = threadIdx.x; i < 64 * R; i += blockDim.x) Ws[i] = W[i];

    const int grp = threadIdx.x >> 5;      // node within block
    const int j   = threadIdx.x & 31;      // feature/output index
    const int node = blockIdx.x * 8 + grp;

    float hv = 0.f, gv = 0.f;
    if (node < N) {
        hv = h[(long long)node * R + j];
        gv = g[(long long)node * R + j];
    }

    if (LIFT) {
        // l2-normalize g row across the 32-lane group
        float s = gv * gv;
        #pragma unroll
        for (int o = 16; o >= 1; o >>= 1) s += __shfl_xor(s, o, 32);
        gv = gv / fmaxf(sqrtf(s), EPSN);
    }

    // stage [h, g] row; producer == consumer wave for hg, but Ws needs block sync
    hg[grp][j]      = hv;
    hg[grp][32 + j] = gv;
    __syncthreads();

    float acc = b[j];
    const float* row = hg[grp];
    #pragma unroll
    for (int k = 0; k < 64; ++k) acc = fmaf(row[k], Ws[k * R + j], acc);

    if (LIFT) {
        float s = acc * acc;
        #pragma unroll
        for (int o = 16; o >= 1; o >>= 1) s += __shfl_xor(s, o, 32);
        acc = acc / fmaxf(sqrtf(s), EPSN);
    } else {
        acc = tanhf(acc);
    }

    if (node < N) out[(long long)node * R + j] = acc;
}

extern "C" void kernel_launch(void* const* d_in, const int* in_sizes, int n_in,
                              void* d_out, int out_size, void* d_ws, size_t ws_size,
                              hipStream_t stream) {
    const float* x      = (const float*)d_in[0];
    const int*   ei     = (const int*)d_in[1];
    const float* ew     = (const float*)d_in[2];
    const float* lift_W = (const float*)d_in[3];
    const float* lift_b = (const float*)d_in[4];
    const float* proj_W = (const float*)d_in[5];
    const float* proj_b = (const float*)d_in[6];

    const int N = in_sizes[0] / R;
    const int E = in_sizes[2];

    float* h0 = (float*)d_ws;
    float* h1 = h0 + (size_t)N * R;
    float* g  = h1 + (size_t)N * R;

    // h0 = x
    hipMemcpyAsync(h0, x, (size_t)N * R * sizeof(float), hipMemcpyDeviceToDevice, stream);

    float* cur = h0;
    float* nxt = h1;

    const int scatter_threads = 256;
    const long long scatter_total = (long long)E * 8;
    const int scatter_blocks = (int)((scatter_total + scatter_threads - 1) / scatter_threads);
    const int node_blocks = (N + 7) / 8;

    for (int l = 0; l < 12; ++l) {
        const bool lift = (l < 8);
        const float* W = lift ? (lift_W + (size_t)l * 64 * R) : (proj_W + (size_t)(l - 8) * 64 * R);
        const float* b = lift ? (lift_b + (size_t)l * R)      : (proj_b + (size_t)(l - 8) * R);

        hipMemsetAsync(g, 0, (size_t)N * R * sizeof(float), stream);
        scatter_kernel<<<scatter_blocks, scatter_threads, 0, stream>>>(cur, ei, ew, g, E);

        float* dst = (l == 11) ? (float*)d_out : nxt;
        if (lift) {
            node_kernel<true><<<node_blocks, 256, 0, stream>>>(cur, g, W, b, dst, N);
        } else {
            node_kernel<false><<<node_blocks, 256, 0, stream>>>(cur, g, W, b, dst, N);
        }
        float* tmp = cur; cur = dst == (float*)d_out ? cur : dst; nxt = tmp;
        if (l < 11) { /* cur/nxt swapped above */ }
    }
}

// Round 2
// 866.992 us; speedup vs baseline: 9.2561x; 9.2561x over previous
//
#include <hip/hip_runtime.h>
#include <math.h>

// LiftProjectNetwork, CSR-gather formulation:
//   build CSR by dst ONCE per call (histogram + scan + fill),
//   then 12 fused layers: g = gather(h, CSR); [normalize g]; out = f([h,g]@W + b)
// N=50000, E=1600000, r=32.

#define R 32
#define EPSN 1e-12f

// ---- CSR build: histogram of dst ----
__global__ void count_kernel(const int* __restrict__ ei, int* __restrict__ counts, int E) {
    int e = blockIdx.x * blockDim.x + threadIdx.x;
    if (e < E) atomicAdd(counts + ei[E + e], 1);
}

// ---- single-block exclusive scan over counts[N] -> offsets[N+1] ----
__global__ void scan_kernel(const int* __restrict__ counts, int* __restrict__ offsets, int N) {
    __shared__ int sums[1024];
    const int tid = threadIdx.x;
    const int chunk = (N + 1023) >> 10;
    const int beg = tid * chunk;
    const int end = min(beg + chunk, N);
    int s = 0;
    for (int i = beg; i < end; ++i) s += counts[i];
    sums[tid] = s;
    __syncthreads();
    for (int off = 1; off < 1024; off <<= 1) {
        int v = (tid >= off) ? sums[tid - off] : 0;
        __syncthreads();
        sums[tid] += v;
        __syncthreads();
    }
    int run = (tid == 0) ? 0 : sums[tid - 1];
    for (int i = beg; i < end; ++i) { offsets[i] = run; run += counts[i]; }
    if (tid == 1023) offsets[N] = sums[1023];
}

// ---- scatter edges into CSR slots (cursor pre-initialized to offsets) ----
__global__ void fill_kernel(const int* __restrict__ ei, const float* __restrict__ ew,
                            int* __restrict__ cursor,
                            int* __restrict__ csr_src, float* __restrict__ csr_w, int E) {
    int e = blockIdx.x * blockDim.x + threadIdx.x;
    if (e >= E) return;
    int p = atomicAdd(cursor + ei[E + e], 1);
    csr_src[p] = ei[e];
    csr_w[p]   = ew[e];
}

// ---- fused layer: gather + (normalize) + [h,g]@W+b + (normalize|tanh) ----
// block = 256 threads = 8 nodes x 32 lanes; lane j owns feature j.
template <bool LIFT>
__global__ void layer_kernel(const float* __restrict__ h,
                             const int* __restrict__ offsets,
                             const int* __restrict__ csr_src,
                             const float* __restrict__ csr_w,
                             const float* __restrict__ W,  // [64*32] (k, j)
                             const float* __restrict__ b,  // [32]
                             float* __restrict__ out,
                             int N) {
    __shared__ float Ws[64 * R];
    __shared__ float hg[8][64];

    for (int i = threadIdx.x; i < 64 * R; i += blockDim.x) Ws[i] = W[i];

    const int grp  = threadIdx.x >> 5;
    const int j    = threadIdx.x & 31;
    const int node = blockIdx.x * 8 + grp;

    float hv = 0.f, g0 = 0.f, g1 = 0.f;
    if (node < N) {
        hv = h[(long long)node * R + j];
        const int beg = offsets[node];
        const int end = offsets[node + 1];
        int e = beg;
        // 4-wide unroll, 2 accumulators for ILP
        for (; e + 4 <= end; e += 4) {
            int   s0 = csr_src[e],   s1 = csr_src[e+1], s2 = csr_src[e+2], s3 = csr_src[e+3];
            float w0 = csr_w[e],     w1 = csr_w[e+1],   w2 = csr_w[e+2],   w3 = csr_w[e+3];
            g0 = fmaf(h[(long long)s0 * R + j], w0, g0);
            g1 = fmaf(h[(long long)s1 * R + j], w1, g1);
            g0 = fmaf(h[(long long)s2 * R + j], w2, g0);
            g1 = fmaf(h[(long long)s3 * R + j], w3, g1);
        }
        for (; e < end; ++e)
            g0 = fmaf(h[(long long)csr_src[e] * R + j], csr_w[e], g0);
    }
    float gv = g0 + g1;

    if (LIFT) {
        float s = gv * gv;
        #pragma unroll
        for (int o = 16; o >= 1; o >>= 1) s += __shfl_xor(s, o, 32);
        gv = gv / fmaxf(sqrtf(s), EPSN);
    }

    hg[grp][j]      = hv;
    hg[grp][32 + j] = gv;
    __syncthreads();

    float acc = b[j];
    const float* row = hg[grp];
    #pragma unroll
    for (int k = 0; k < 64; ++k) acc = fmaf(row[k], Ws[k * R + j], acc);

    if (LIFT) {
        float s = acc * acc;
        #pragma unroll
        for (int o = 16; o >= 1; o >>= 1) s += __shfl_xor(s, o, 32);
        acc = acc / fmaxf(sqrtf(s), EPSN);
    } else {
        acc = tanhf(acc);
    }

    if (node < N) out[(long long)node * R + j] = acc;
}

extern "C" void kernel_launch(void* const* d_in, const int* in_sizes, int n_in,
                              void* d_out, int out_size, void* d_ws, size_t ws_size,
                              hipStream_t stream) {
    const float* x      = (const float*)d_in[0];
    const int*   ei     = (const int*)d_in[1];
    const float* ew     = (const float*)d_in[2];
    const float* lift_W = (const float*)d_in[3];
    const float* lift_b = (const float*)d_in[4];
    const float* proj_W = (const float*)d_in[5];
    const float* proj_b = (const float*)d_in[6];

    const int N = in_sizes[0] / R;
    const int E = in_sizes[2];

    // workspace layout
    float* h0      = (float*)d_ws;
    float* h1      = h0 + (size_t)N * R;
    int*   counts  = (int*)(h1 + (size_t)N * R);
    int*   offsets = counts + N;
    int*   cursor  = offsets + N + 1;
    int*   csr_src = cursor + N;
    float* csr_w   = (float*)(csr_src + E);

    // ---- CSR build (once, reused by all 12 layers) ----
    hipMemsetAsync(counts, 0, (size_t)N * sizeof(int), stream);
    count_kernel<<<(E + 255) / 256, 256, 0, stream>>>(ei, counts, E);
    scan_kernel<<<1, 1024, 0, stream>>>(counts, offsets, N);
    hipMemcpyAsync(cursor, offsets, (size_t)N * sizeof(int), hipMemcpyDeviceToDevice, stream);
    fill_kernel<<<(E + 255) / 256, 256, 0, stream>>>(ei, ew, cursor, csr_src, csr_w, E);

    // ---- 12 fused layers ----
    const float* cur = x;
    float* buf[2] = {h0, h1};
    const int node_blocks = (N + 7) / 8;

    for (int l = 0; l < 12; ++l) {
        const bool lift = (l < 8);
        const float* W = lift ? (lift_W + (size_t)l * 64 * R) : (proj_W + (size_t)(l - 8) * 64 * R);
        const float* b = lift ? (lift_b + (size_t)l * R)      : (proj_b + (size_t)(l - 8) * R);
        float* dst = (l == 11) ? (float*)d_out : buf[l & 1];
        if (lift)
            layer_kernel<true ><<<node_blocks, 256, 0, stream>>>(cur, offsets, csr_src, csr_w, W, b, dst, N);
        else
            layer_kernel<false><<<node_blocks, 256, 0, stream>>>(cur, offsets, csr_src, csr_w, W, b, dst, N);
        cur = dst;
    }
}